// Round 6
// baseline (302.761 us; speedup 1.0000x reference)
//
#include <hip/hip_runtime.h>
#include <cstdint>
#include <cstddef>

#define B_  8
#define T_  12
#define N_  250
#define D_  64
#define H_  8
#define HD_ 8

typedef short     bf16x8  __attribute__((ext_vector_type(8)));
typedef float     f32x16  __attribute__((ext_vector_type(16)));
typedef unsigned  u32x4   __attribute__((ext_vector_type(4)));
typedef float     f32x4u  __attribute__((ext_vector_type(4), aligned(4)));

#if __has_builtin(__builtin_amdgcn_exp2f)
#define EXP2(x) __builtin_amdgcn_exp2f(x)
#else
#define EXP2(x) exp2f(x)
#endif

__device__ __forceinline__ uint16_t f2bf(float f) {
    uint32_t u = __builtin_bit_cast(uint32_t, f);
    uint32_t r = (u + 0x7FFFu + ((u >> 16) & 1u)) >> 16;   // RNE
    return (uint16_t)r;
}

// ---------------- Kernel A: QKV projection -> bf16 operand buffers ----------
// qbh/kbh: [bt*8+h][256 rows (250 used)][8] bf16, row-major 16B rows.
// vbh:     [bt*8+h][8 d][256 m]            bf16 (V transposed per head).
__global__ __launch_bounds__(256) void qkv_kernel(
    const float* __restrict__ x,
    const float* __restrict__ Wq, const float* __restrict__ bq,
    const float* __restrict__ Wk, const float* __restrict__ bk,
    const float* __restrict__ Wv, const float* __restrict__ bv,
    uint16_t* __restrict__ qbh, uint16_t* __restrict__ kbh,
    uint16_t* __restrict__ vbh)
{
    __shared__ float WqT[64*64];
    __shared__ float WkT[64*64];
    __shared__ float WvT[64*64];
    __shared__ float xT[4][64][8];

    int tid = threadIdx.x;
    for (int i = tid; i < 4096; i += 256) {
        int d = i >> 6, j = i & 63;
        WqT[j*64 + d] = Wq[i];
        WkT[j*64 + d] = Wk[i];
        WvT[j*64 + d] = Wv[i];
    }
    __syncthreads();

    int wave = tid >> 6, lane = tid & 63;
    int row0 = blockIdx.x * 32 + wave * 8;   // 750*32 = 24000 rows

    #pragma unroll
    for (int rr = 0; rr < 8; ++rr)
        xT[wave][lane][rr] = x[(size_t)(row0 + rr)*64 + lane];

    float accq[8], acck[8], accv[8];
    float bqv = bq[lane], bkv = bk[lane], bvv = bv[lane];
    #pragma unroll
    for (int rr = 0; rr < 8; ++rr) { accq[rr]=bqv; acck[rr]=bkv; accv[rr]=bvv; }

    #pragma unroll 8
    for (int j = 0; j < 64; ++j) {
        float4 xa = *(const float4*)&xT[wave][j][0];
        float4 xb = *(const float4*)&xT[wave][j][4];
        float wq = WqT[j*64 + lane];
        float wk = WkT[j*64 + lane];
        float wv = WvT[j*64 + lane];
        float xr[8] = {xa.x, xa.y, xa.z, xa.w, xb.x, xb.y, xb.z, xb.w};
        #pragma unroll
        for (int rr = 0; rr < 8; ++rr) {
            accq[rr] = fmaf(xr[rr], wq, accq[rr]);
            acck[rr] = fmaf(xr[rr], wk, acck[rr]);
            accv[rr] = fmaf(xr[rr], wv, accv[rr]);
        }
    }

    int h = lane >> 3, dh = lane & 7;
    #pragma unroll
    for (int rr = 0; rr < 8; ++rr) {
        int row = row0 + rr;
        int bt = row / 250;
        int nn = row - bt*250;
        size_t hb = (size_t)(bt*8 + h);
        qbh[(hb*256 + nn)*8 + dh] = f2bf(accq[rr]);
        kbh[(hb*256 + nn)*8 + dh] = f2bf(acck[rr]);
        vbh[(hb*8 + dh)*256 + nn] = f2bf(accv[rr]);
    }
}

// ---------------- Kernel B: MFMA windowed attention, all 3 ti fused --------
// grid = (b,t,h,strip) = 3072 blocks x 128 thr (2 waves; wave = 32-n tile).
// S01 = mfma(K[t-1],Q) shared by ti0/ti1 (scales differ); S2 = mfma(K[t],Q).
// Three independent softmax+PV chains per wave -> high ILP, no LDS.
__global__ __launch_bounds__(128, 2) void attn_kernel(
    const uint16_t* __restrict__ qbh, const uint16_t* __restrict__ kbh,
    const uint16_t* __restrict__ vbh, const float* __restrict__ adj,
    float* __restrict__ hs)
{
    const float S0e = 0.51006972338f;    // 8^-0.5 * log2(e)
    const float S1e = 0.18033688011f;    // 8^-1   * log2(e)
    const float S2e = 0.06375872168f;    // 8^-1.5 * log2(e)

    int tid  = threadIdx.x;
    int nt   = tid >> 6;          // wave id = n-tile within strip
    int lane = tid & 63;
    int ln31 = lane & 31, hi = lane >> 5;

    int idx = blockIdx.x;
    int strip = idx & 3; idx >>= 2;
    int h  = idx & 7; idx >>= 3;
    int t  = idx % 12;
    int b  = idx / 12;

    int tm1 = (t + 11) % 12;
    int tp1 = (t + 1) % 12;

    const uint16_t* qh  = qbh + ((size_t)((b*12 + t  )*8 + h) * 256) * 8;
    const uint16_t* kh1 = kbh + ((size_t)((b*12 + tm1)*8 + h) * 256) * 8;
    const uint16_t* kh2 = kbh + ((size_t)((b*12 + t  )*8 + h) * 256) * 8;
    const uint16_t* vh1 = vbh + ((size_t)((b*12 + tm1)*8 + h) * 8) * 256;
    const uint16_t* vh2 = vbh + ((size_t)((b*12 + t  )*8 + h) * 8) * 256;

    int n0 = strip*64 + nt*32;
    int n  = n0 + ln31;
    int nc = n > 249 ? 249 : n;

    const float* ar0 = adj + ((size_t)(b*12 + tm1) * 62500) + (size_t)nc * 250;
    const float* ar1 = adj + ((size_t)(b*12 + t  ) * 62500) + (size_t)nc * 250;
    const float* ar2 = adj + ((size_t)(b*12 + tp1) * 62500) + (size_t)nc * 250;

    // Q B-frag: col n, k=d (hi half -> k 8..15 unused, zero)
    bf16x8 qf = *(const bf16x8*)(qh + (size_t)n * 8);
    bf16x8 z8 = {0,0,0,0,0,0,0,0};
    if (hi) qf = z8;

    f32x16 acc0, acc1, acc2, zc;
    #pragma unroll
    for (int i = 0; i < 16; ++i) { acc0[i]=0.f; acc1[i]=0.f; acc2[i]=0.f; zc[i]=0.f; }
    float z0 = 0.f, z1 = 0.f, z2 = 0.f;
    int vrow = ln31 & 7;
    bool vzero = (ln31 >= 8);

    #pragma unroll
    for (int mt = 0; mt < 8; ++mt) {
        int m0 = mt * 32;
        bf16x8 kf1 = *(const bf16x8*)(kh1 + (size_t)(m0 + ln31) * 8);
        bf16x8 kf2 = *(const bf16x8*)(kh2 + (size_t)(m0 + ln31) * 8);
        if (hi) { kf1 = z8; kf2 = z8; }
        f32x16 s01 = __builtin_amdgcn_mfma_f32_32x32x16_bf16(kf1, qf, zc, 0, 0, 0);
        f32x16 s2  = __builtin_amdgcn_mfma_f32_32x32x16_bf16(kf2, qf, zc, 0, 0, 0);

        bf16x8 vf1a = *(const bf16x8*)(vh1 + (size_t)vrow*256 + m0 + hi*8);
        bf16x8 vf1b = *(const bf16x8*)(vh1 + (size_t)vrow*256 + m0 + 16 + hi*8);
        bf16x8 vf2a = *(const bf16x8*)(vh2 + (size_t)vrow*256 + m0 + hi*8);
        bf16x8 vf2b = *(const bf16x8*)(vh2 + (size_t)vrow*256 + m0 + 16 + hi*8);
        if (vzero) { vf1a = z8; vf1b = z8; vf2a = z8; vf2b = z8; }

        auto do_ti = [&](const f32x16& s, float sc, const float* arow,
                         float& z, f32x16& acc, bf16x8 vfA, bf16x8 vfB) {
            // adj gather: m-offsets {0,8,16,24}+4*hi, 4 consecutive each
            f32x4u a0 = *(const f32x4u*)(arow + m0 +      4*hi);
            f32x4u a1 = *(const f32x4u*)(arow + m0 +  8 + 4*hi);
            f32x4u a2 = *(const f32x4u*)(arow + m0 + 16 + 4*hi);
            f32x4u a3 = *(const f32x4u*)(arow + m0 + 24 + 4*hi);

            unsigned w[8];
            #pragma unroll
            for (int e = 0; e < 8; ++e) {
                int r0 = 2*e, r1 = 2*e + 1;
                float p0 = EXP2(s[r0] * sc);
                float p1 = EXP2(s[r1] * sc);
                float av0 = (r0 < 4) ? a0[r0 & 3] : (r0 < 8) ? a1[r0 & 3]
                          : (r0 < 12) ? a2[r0 & 3] : a3[r0 & 3];
                float av1 = (r1 < 4) ? a0[r1 & 3] : (r1 < 8) ? a1[r1 & 3]
                          : (r1 < 12) ? a2[r1 & 3] : a3[r1 & 3];
                if (mt == 7) {   // mask m-pad 250..255 (zero BOTH p and av)
                    int c0 = (r0 & 3) + 8*(r0 >> 2) + 4*hi;
                    int c1 = (r1 & 3) + 8*(r1 >> 2) + 4*hi;
                    if (224 + c0 >= 250) { p0 = 0.f; av0 = 0.f; }
                    if (224 + c1 >= 250) { p1 = 0.f; av1 = 0.f; }
                }
                z += p0; z += p1;
                float pa0 = p0 * av0, pa1 = p1 * av1;
                asm("v_cvt_pk_bf16_f32 %0, %1, %2"
                    : "=v"(w[e]) : "v"(pa0), "v"(pa1));
            }
            // half-swaps: (w0..w3) = P^T k 0..15, (w4..w7) = k 16..31
            asm volatile("v_permlane32_swap_b32 %0, %1" : "+v"(w[2]), "+v"(w[0]));
            asm volatile("v_permlane32_swap_b32 %0, %1" : "+v"(w[3]), "+v"(w[1]));
            asm volatile("v_permlane32_swap_b32 %0, %1" : "+v"(w[6]), "+v"(w[4]));
            asm volatile("v_permlane32_swap_b32 %0, %1" : "+v"(w[7]), "+v"(w[5]));

            u32x4 t1 = {w[0], w[1], w[2], w[3]};
            u32x4 t2 = {w[4], w[5], w[6], w[7]};
            bf16x8 pf1 = __builtin_bit_cast(bf16x8, t1);
            bf16x8 pf2 = __builtin_bit_cast(bf16x8, t2);

            acc = __builtin_amdgcn_mfma_f32_32x32x16_bf16(vfA, pf1, acc, 0, 0, 0);
            acc = __builtin_amdgcn_mfma_f32_32x32x16_bf16(vfB, pf2, acc, 0, 0, 0);
        };

        do_ti(s01, S0e, ar0, z0, acc0, vf1a, vf1b);
        do_ti(s01, S1e, ar1, z1, acc1, vf1a, vf1b);
        do_ti(s2,  S2e, ar2, z2, acc2, vf2a, vf2b);
    }

    float zf0 = z0 + __shfl_xor(z0, 32);
    float zf1 = z1 + __shfl_xor(z1, 32);
    float zf2 = z2 + __shfl_xor(z2, 32);
    float i0 = 1.0f / zf0, i1 = 1.0f / zf1, i2 = 1.0f / zf2;

    if (n < 250) {
        size_t base = ((size_t)b*36 + t)*250;   // + ti*12*250 below
        float4 o0, o1, o2;
        o0.x = acc0[0]*i0; o0.y = acc0[1]*i0; o0.z = acc0[2]*i0; o0.w = acc0[3]*i0;
        o1.x = acc1[0]*i1; o1.y = acc1[1]*i1; o1.z = acc1[2]*i1; o1.w = acc1[3]*i1;
        o2.x = acc2[0]*i2; o2.y = acc2[1]*i2; o2.z = acc2[2]*i2; o2.w = acc2[3]*i2;
        *(float4*)(hs + (((base + 0*3000) + n)*64 + h*8 + hi*4)) = o0;
        *(float4*)(hs + (((base + 1*3000) + n)*64 + h*8 + hi*4)) = o1;
        *(float4*)(hs + (((base + 2*3000) + n)*64 + h*8 + hi*4)) = o2;
    }
}

// ---------------- Kernel C: Wd head + residual + LayerNorm ----------------
__global__ __launch_bounds__(256) void out_kernel(
    const float* __restrict__ hsb, const float* __restrict__ x,
    const float* __restrict__ Wd, const float* __restrict__ bd,
    const float* __restrict__ gamma, const float* __restrict__ beta,
    float* __restrict__ out)
{
    __shared__ float hl[36*64];
    __shared__ float xl[12*64];

    int bn = blockIdx.x;
    int n = bn % 250, b = bn / 250;
    int tid = threadIdx.x;

    for (int i = tid; i < 36*64; i += 256) {
        int tw = i >> 6, d = i & 63;
        hl[i] = hsb[((size_t)(b*36 + tw)*250 + n)*64 + d];
    }
    for (int i = tid; i < 12*64; i += 256) {
        int t = i >> 6, d = i & 63;
        xl[i] = x[((size_t)(b*12 + t)*250 + n)*64 + d];
    }
    __syncthreads();

    int lane = tid & 63, wv = tid >> 6;
    float gg = gamma[lane], bb = beta[lane];

    for (int t = wv; t < 12; t += 4) {
        float acc = bd[t];
        const float* wd = Wd + t*36;
        #pragma unroll
        for (int tw = 0; tw < 36; ++tw)
            acc = fmaf(wd[tw], hl[tw*64 + lane], acc);
        float y = acc + xl[t*64 + lane];

        float s = y, s2 = y*y;
        #pragma unroll
        for (int o = 32; o >= 1; o >>= 1) {
            s  += __shfl_xor(s, o);
            s2 += __shfl_xor(s2, o);
        }
        float mu  = s * 0.015625f;
        float var = s2 * 0.015625f - mu*mu;
        out[((size_t)(b*12 + t)*250 + n)*64 + lane] =
            gg * (y - mu) * rsqrtf(var + 1e-5f) + bb;
    }
}

extern "C" void kernel_launch(void* const* d_in, const int* in_sizes, int n_in,
                              void* d_out, int out_size, void* d_ws, size_t ws_size,
                              hipStream_t stream)
{
    const float* x    = (const float*)d_in[0];
    // d_in[1] = ste : unused by the reference
    const float* adj  = (const float*)d_in[2];
    const float* Wq   = (const float*)d_in[3];
    const float* bq   = (const float*)d_in[4];
    const float* Wk   = (const float*)d_in[5];
    const float* bk   = (const float*)d_in[6];
    const float* Wv   = (const float*)d_in[7];
    const float* bv   = (const float*)d_in[8];
    const float* Wd   = (const float*)d_in[9];
    const float* bd   = (const float*)d_in[10];
    const float* gam  = (const float*)d_in[11];
    const float* bet  = (const float*)d_in[12];
    float* out = (float*)d_out;

    // ws layout (bytes): hs f32 [18,432,000] | qbh | kbh | vbh (bf16, each
    // 96*8 heads * 2048 elems = 3,145,728 B).
    float*    hs  = (float*)d_ws;
    uint16_t* qbh = (uint16_t*)((char*)d_ws + 18432000);
    uint16_t* kbh = qbh + 1572864;
    uint16_t* vbh = kbh + 1572864;

    qkv_kernel<<<750, 256, 0, stream>>>(x, Wq, bq, Wk, bk, Wv, bv, qbh, kbh, vbh);
    attn_kernel<<<B_*T_*H_*4, 128, 0, stream>>>(qbh, kbh, vbh, adj, hs);
    out_kernel<<<B_*N_, 256, 0, stream>>>(hs, x, Wd, bd, gam, bet, out);
}

// Round 8
// 141.485 us; speedup vs baseline: 2.1399x; 2.1399x over previous
//
#include <hip/hip_runtime.h>
#include <cstdint>
#include <cstddef>

#define B_  8
#define T_  12
#define N_  250
#define D_  64
#define H_  8
#define HD_ 8

typedef short     bf16x8  __attribute__((ext_vector_type(8)));
typedef float     f32x16  __attribute__((ext_vector_type(16)));
typedef unsigned  u32x4   __attribute__((ext_vector_type(4)));
typedef float     f32x4u  __attribute__((ext_vector_type(4), aligned(4)));

#if __has_builtin(__builtin_amdgcn_exp2f)
#define EXP2(x) __builtin_amdgcn_exp2f(x)
#else
#define EXP2(x) exp2f(x)
#endif

__device__ __forceinline__ uint16_t f2bf(float f) {
    uint32_t u = __builtin_bit_cast(uint32_t, f);
    uint32_t r = (u + 0x7FFFu + ((u >> 16) & 1u)) >> 16;   // RNE
    return (uint16_t)r;
}

// ---------------- Kernel A: QKV projection -> bf16 operand buffers ----------
// qbh/kbh: [bt*8+h][256 rows (250 used)][8] bf16, row-major 16B rows.
// vbh:     [bt*8+h][8 d][256 m]            bf16 (V transposed per head).
__global__ __launch_bounds__(256) void qkv_kernel(
    const float* __restrict__ x,
    const float* __restrict__ Wq, const float* __restrict__ bq,
    const float* __restrict__ Wk, const float* __restrict__ bk,
    const float* __restrict__ Wv, const float* __restrict__ bv,
    uint16_t* __restrict__ qbh, uint16_t* __restrict__ kbh,
    uint16_t* __restrict__ vbh)
{
    __shared__ float WqT[64*64];
    __shared__ float WkT[64*64];
    __shared__ float WvT[64*64];
    __shared__ float xT[4][64][8];

    int tid = threadIdx.x;
    for (int i = tid; i < 4096; i += 256) {
        int d = i >> 6, j = i & 63;
        WqT[j*64 + d] = Wq[i];
        WkT[j*64 + d] = Wk[i];
        WvT[j*64 + d] = Wv[i];
    }
    __syncthreads();

    int wave = tid >> 6, lane = tid & 63;
    int row0 = blockIdx.x * 32 + wave * 8;   // 750*32 = 24000 rows

    #pragma unroll
    for (int rr = 0; rr < 8; ++rr)
        xT[wave][lane][rr] = x[(size_t)(row0 + rr)*64 + lane];

    float accq[8], acck[8], accv[8];
    float bqv = bq[lane], bkv = bk[lane], bvv = bv[lane];
    #pragma unroll
    for (int rr = 0; rr < 8; ++rr) { accq[rr]=bqv; acck[rr]=bkv; accv[rr]=bvv; }

    #pragma unroll 8
    for (int j = 0; j < 64; ++j) {
        float4 xa = *(const float4*)&xT[wave][j][0];
        float4 xb = *(const float4*)&xT[wave][j][4];
        float wq = WqT[j*64 + lane];
        float wk = WkT[j*64 + lane];
        float wv = WvT[j*64 + lane];
        float xr[8] = {xa.x, xa.y, xa.z, xa.w, xb.x, xb.y, xb.z, xb.w};
        #pragma unroll
        for (int rr = 0; rr < 8; ++rr) {
            accq[rr] = fmaf(xr[rr], wq, accq[rr]);
            acck[rr] = fmaf(xr[rr], wk, acck[rr]);
            accv[rr] = fmaf(xr[rr], wv, accv[rr]);
        }
    }

    int h = lane >> 3, dh = lane & 7;
    #pragma unroll
    for (int rr = 0; rr < 8; ++rr) {
        int row = row0 + rr;
        int bt = row / 250;
        int nn = row - bt*250;
        size_t hb = (size_t)(bt*8 + h);
        qbh[(hb*256 + nn)*8 + dh] = f2bf(accq[rr]);
        kbh[(hb*256 + nn)*8 + dh] = f2bf(acck[rr]);
        vbh[(hb*8 + dh)*256 + nn] = f2bf(accv[rr]);
    }
}

// ---------------- Kernel B: MFMA windowed attention ----------------
// Derived from R6's PASSING 3-chain kernel by deleting chain2 from the fused
// block and moving it to which=1 blocks. Same lambda structure, same
// launch_bounds(128,2), same data environment as R6.
// grid = (b,t,h,which,strip) = 6144 blocks x 128 thr (2 waves, wave=32-n tile)
// which=0: ti0+ti1 share S01=mfma(K[t-1],Q) and K/V loads; 2 acc chains.
// which=1: ti2 alone (K/V at t).
__global__ __launch_bounds__(128, 2) void attn_kernel(
    const uint16_t* __restrict__ qbh, const uint16_t* __restrict__ kbh,
    const uint16_t* __restrict__ vbh, const float* __restrict__ adj,
    float* __restrict__ hs)
{
    const float S0e = 0.51006972338f;    // 8^-0.5 * log2(e)
    const float S1e = 0.18033688011f;    // 8^-1   * log2(e)
    const float S2e = 0.06375872168f;    // 8^-1.5 * log2(e)

    int tid  = threadIdx.x;
    int nt   = tid >> 6;
    int lane = tid & 63;
    int ln31 = lane & 31, hi = lane >> 5;

    int idx = blockIdx.x;
    int strip = idx & 3; idx >>= 2;
    int which = idx & 1; idx >>= 1;
    int h  = idx & 7; idx >>= 3;
    int t  = idx % 12;
    int b  = idx / 12;

    int tm1 = (t + 11) % 12;
    int tp1 = (t + 1) % 12;
    int t_k = which ? t : tm1;

    const uint16_t* qh = qbh + ((size_t)((b*12 + t  )*8 + h) * 256) * 8;
    const uint16_t* kh = kbh + ((size_t)((b*12 + t_k)*8 + h) * 256) * 8;
    const uint16_t* vh = vbh + ((size_t)((b*12 + t_k)*8 + h) * 8) * 256;

    int n0 = strip*64 + nt*32;
    int n  = n0 + ln31;
    int nc = n > 249 ? 249 : n;

    bf16x8 qf = *(const bf16x8*)(qh + (size_t)n * 8);
    bf16x8 z8 = {0,0,0,0,0,0,0,0};
    if (hi) qf = z8;

    f32x16 zc;
    #pragma unroll
    for (int i = 0; i < 16; ++i) zc[i] = 0.f;
    int vrow = ln31 & 7;
    bool vzero = (ln31 >= 8);
    size_t obase = ((size_t)b*36 + t)*250;   // + ti*3000

    if (which == 0) {
        const float* ar0 = adj + ((size_t)(b*12 + tm1) * 62500) + (size_t)nc * 250;
        const float* ar1 = adj + ((size_t)(b*12 + t  ) * 62500) + (size_t)nc * 250;

        f32x16 acc0 = zc, acc1 = zc;
        float z0 = 0.f, z1 = 0.f;

        #pragma unroll
        for (int mt = 0; mt < 8; ++mt) {
            int m0 = mt * 32;
            bf16x8 kf = *(const bf16x8*)(kh + (size_t)(m0 + ln31) * 8);
            if (hi) kf = z8;
            f32x16 s01 = __builtin_amdgcn_mfma_f32_32x32x16_bf16(kf, qf, zc, 0, 0, 0);

            bf16x8 vfa = *(const bf16x8*)(vh + (size_t)vrow*256 + m0 + hi*8);
            bf16x8 vfb = *(const bf16x8*)(vh + (size_t)vrow*256 + m0 + 16 + hi*8);
            if (vzero) { vfa = z8; vfb = z8; }

            auto do_ti = [&](const f32x16& s, float sc, const float* arow,
                             float& z, f32x16& acc, bf16x8 vfA, bf16x8 vfB) {
                f32x4u a0 = *(const f32x4u*)(arow + m0 +      4*hi);
                f32x4u a1 = *(const f32x4u*)(arow + m0 +  8 + 4*hi);
                f32x4u a2 = *(const f32x4u*)(arow + m0 + 16 + 4*hi);
                f32x4u a3 = *(const f32x4u*)(arow + m0 + 24 + 4*hi);

                unsigned w[8];
                #pragma unroll
                for (int e = 0; e < 8; ++e) {
                    int r0 = 2*e, r1 = 2*e + 1;
                    float p0 = EXP2(s[r0] * sc);
                    float p1 = EXP2(s[r1] * sc);
                    float av0 = (r0 < 4) ? a0[r0 & 3] : (r0 < 8) ? a1[r0 & 3]
                              : (r0 < 12) ? a2[r0 & 3] : a3[r0 & 3];
                    float av1 = (r1 < 4) ? a0[r1 & 3] : (r1 < 8) ? a1[r1 & 3]
                              : (r1 < 12) ? a2[r1 & 3] : a3[r1 & 3];
                    if (mt == 7) {   // mask m-pad 250..255 (zero BOTH p and av)
                        int c0 = (r0 & 3) + 8*(r0 >> 2) + 4*hi;
                        int c1 = (r1 & 3) + 8*(r1 >> 2) + 4*hi;
                        if (224 + c0 >= 250) { p0 = 0.f; av0 = 0.f; }
                        if (224 + c1 >= 250) { p1 = 0.f; av1 = 0.f; }
                    }
                    z += p0; z += p1;
                    float pa0 = p0 * av0, pa1 = p1 * av1;
                    asm("v_cvt_pk_bf16_f32 %0, %1, %2"
                        : "=v"(w[e]) : "v"(pa0), "v"(pa1));
                }
                asm volatile("v_permlane32_swap_b32 %0, %1" : "+v"(w[2]), "+v"(w[0]));
                asm volatile("v_permlane32_swap_b32 %0, %1" : "+v"(w[3]), "+v"(w[1]));
                asm volatile("v_permlane32_swap_b32 %0, %1" : "+v"(w[6]), "+v"(w[4]));
                asm volatile("v_permlane32_swap_b32 %0, %1" : "+v"(w[7]), "+v"(w[5]));

                u32x4 t1 = {w[0], w[1], w[2], w[3]};
                u32x4 t2 = {w[4], w[5], w[6], w[7]};
                bf16x8 pf1 = __builtin_bit_cast(bf16x8, t1);
                bf16x8 pf2 = __builtin_bit_cast(bf16x8, t2);

                acc = __builtin_amdgcn_mfma_f32_32x32x16_bf16(vfA, pf1, acc, 0, 0, 0);
                acc = __builtin_amdgcn_mfma_f32_32x32x16_bf16(vfB, pf2, acc, 0, 0, 0);
            };

            do_ti(s01, S0e, ar0, z0, acc0, vfa, vfb);
            do_ti(s01, S1e, ar1, z1, acc1, vfa, vfb);
        }

        float zf0 = z0 + __shfl_xor(z0, 32);
        float zf1 = z1 + __shfl_xor(z1, 32);
        float i0 = 1.0f / zf0, i1 = 1.0f / zf1;
        if (n < 250) {
            float4 o0, o1;
            o0.x = acc0[0]*i0; o0.y = acc0[1]*i0; o0.z = acc0[2]*i0; o0.w = acc0[3]*i0;
            o1.x = acc1[0]*i1; o1.y = acc1[1]*i1; o1.z = acc1[2]*i1; o1.w = acc1[3]*i1;
            *(float4*)(hs + ((obase +    0 + n)*64 + h*8 + hi*4)) = o0;
            *(float4*)(hs + ((obase + 3000 + n)*64 + h*8 + hi*4)) = o1;
        }
    } else {
        const float* ar2 = adj + ((size_t)(b*12 + tp1) * 62500) + (size_t)nc * 250;

        f32x16 acc2 = zc;
        float z2 = 0.f;

        #pragma unroll
        for (int mt = 0; mt < 8; ++mt) {
            int m0 = mt * 32;
            bf16x8 kf = *(const bf16x8*)(kh + (size_t)(m0 + ln31) * 8);
            if (hi) kf = z8;
            f32x16 s2 = __builtin_amdgcn_mfma_f32_32x32x16_bf16(kf, qf, zc, 0, 0, 0);

            bf16x8 vfa = *(const bf16x8*)(vh + (size_t)vrow*256 + m0 + hi*8);
            bf16x8 vfb = *(const bf16x8*)(vh + (size_t)vrow*256 + m0 + 16 + hi*8);
            if (vzero) { vfa = z8; vfb = z8; }

            auto do_ti = [&](const f32x16& s, float sc, const float* arow,
                             float& z, f32x16& acc, bf16x8 vfA, bf16x8 vfB) {
                f32x4u a0 = *(const f32x4u*)(arow + m0 +      4*hi);
                f32x4u a1 = *(const f32x4u*)(arow + m0 +  8 + 4*hi);
                f32x4u a2 = *(const f32x4u*)(arow + m0 + 16 + 4*hi);
                f32x4u a3 = *(const f32x4u*)(arow + m0 + 24 + 4*hi);

                unsigned w[8];
                #pragma unroll
                for (int e = 0; e < 8; ++e) {
                    int r0 = 2*e, r1 = 2*e + 1;
                    float p0 = EXP2(s[r0] * sc);
                    float p1 = EXP2(s[r1] * sc);
                    float av0 = (r0 < 4) ? a0[r0 & 3] : (r0 < 8) ? a1[r0 & 3]
                              : (r0 < 12) ? a2[r0 & 3] : a3[r0 & 3];
                    float av1 = (r1 < 4) ? a0[r1 & 3] : (r1 < 8) ? a1[r1 & 3]
                              : (r1 < 12) ? a2[r1 & 3] : a3[r1 & 3];
                    if (mt == 7) {
                        int c0 = (r0 & 3) + 8*(r0 >> 2) + 4*hi;
                        int c1 = (r1 & 3) + 8*(r1 >> 2) + 4*hi;
                        if (224 + c0 >= 250) { p0 = 0.f; av0 = 0.f; }
                        if (224 + c1 >= 250) { p1 = 0.f; av1 = 0.f; }
                    }
                    z += p0; z += p1;
                    float pa0 = p0 * av0, pa1 = p1 * av1;
                    asm("v_cvt_pk_bf16_f32 %0, %1, %2"
                        : "=v"(w[e]) : "v"(pa0), "v"(pa1));
                }
                asm volatile("v_permlane32_swap_b32 %0, %1" : "+v"(w[2]), "+v"(w[0]));
                asm volatile("v_permlane32_swap_b32 %0, %1" : "+v"(w[3]), "+v"(w[1]));
                asm volatile("v_permlane32_swap_b32 %0, %1" : "+v"(w[6]), "+v"(w[4]));
                asm volatile("v_permlane32_swap_b32 %0, %1" : "+v"(w[7]), "+v"(w[5]));

                u32x4 t1 = {w[0], w[1], w[2], w[3]};
                u32x4 t2 = {w[4], w[5], w[6], w[7]};
                bf16x8 pf1 = __builtin_bit_cast(bf16x8, t1);
                bf16x8 pf2 = __builtin_bit_cast(bf16x8, t2);

                acc = __builtin_amdgcn_mfma_f32_32x32x16_bf16(vfA, pf1, acc, 0, 0, 0);
                acc = __builtin_amdgcn_mfma_f32_32x32x16_bf16(vfB, pf2, acc, 0, 0, 0);
            };

            do_ti(s2, S2e, ar2, z2, acc2, vfa, vfb);
        }

        float zf2 = z2 + __shfl_xor(z2, 32);
        float i2 = 1.0f / zf2;
        if (n < 250) {
            float4 o2;
            o2.x = acc2[0]*i2; o2.y = acc2[1]*i2; o2.z = acc2[2]*i2; o2.w = acc2[3]*i2;
            *(float4*)(hs + ((obase + 6000 + n)*64 + h*8 + hi*4)) = o2;
        }
    }
}

// ---------------- Kernel C: Wd head + residual + LayerNorm ----------------
__global__ __launch_bounds__(256) void out_kernel(
    const float* __restrict__ hsb, const float* __restrict__ x,
    const float* __restrict__ Wd, const float* __restrict__ bd,
    const float* __restrict__ gamma, const float* __restrict__ beta,
    float* __restrict__ out)
{
    __shared__ float hl[36*64];
    __shared__ float xl[12*64];

    int bn = blockIdx.x;
    int n = bn % 250, b = bn / 250;
    int tid = threadIdx.x;

    for (int i = tid; i < 36*64; i += 256) {
        int tw = i >> 6, d = i & 63;
        hl[i] = hsb[((size_t)(b*36 + tw)*250 + n)*64 + d];
    }
    for (int i = tid; i < 12*64; i += 256) {
        int t = i >> 6, d = i & 63;
        xl[i] = x[((size_t)(b*12 + t)*250 + n)*64 + d];
    }
    __syncthreads();

    int lane = tid & 63, wv = tid >> 6;
    float gg = gamma[lane], bb = beta[lane];

    for (int t = wv; t < 12; t += 4) {
        float acc = bd[t];
        const float* wd = Wd + t*36;
        #pragma unroll
        for (int tw = 0; tw < 36; ++tw)
            acc = fmaf(wd[tw], hl[tw*64 + lane], acc);
        float y = acc + xl[t*64 + lane];

        float s = y, s2 = y*y;
        #pragma unroll
        for (int o = 32; o >= 1; o >>= 1) {
            s  += __shfl_xor(s, o);
            s2 += __shfl_xor(s2, o);
        }
        float mu  = s * 0.015625f;
        float var = s2 * 0.015625f - mu*mu;
        out[((size_t)(b*12 + t)*250 + n)*64 + lane] =
            gg * (y - mu) * rsqrtf(var + 1e-5f) + bb;
    }
}

extern "C" void kernel_launch(void* const* d_in, const int* in_sizes, int n_in,
                              void* d_out, int out_size, void* d_ws, size_t ws_size,
                              hipStream_t stream)
{
    const float* x    = (const float*)d_in[0];
    // d_in[1] = ste : unused by the reference
    const float* adj  = (const float*)d_in[2];
    const float* Wq   = (const float*)d_in[3];
    const float* bq   = (const float*)d_in[4];
    const float* Wk   = (const float*)d_in[5];
    const float* bk   = (const float*)d_in[6];
    const float* Wv   = (const float*)d_in[7];
    const float* bv   = (const float*)d_in[8];
    const float* Wd   = (const float*)d_in[9];
    const float* bd   = (const float*)d_in[10];
    const float* gam  = (const float*)d_in[11];
    const float* bet  = (const float*)d_in[12];
    float* out = (float*)d_out;

    // ws layout (bytes): hs f32 [18,432,000] | qbh | kbh | vbh (bf16, each
    // 96*8 heads * 2048 elems = 3,145,728 B).
    float*    hs  = (float*)d_ws;
    uint16_t* qbh = (uint16_t*)((char*)d_ws + 18432000);
    uint16_t* kbh = qbh + 1572864;
    uint16_t* vbh = kbh + 1572864;

    qkv_kernel<<<750, 256, 0, stream>>>(x, Wq, bq, Wk, bk, Wv, bv, qbh, kbh, vbh);
    attn_kernel<<<B_*T_*H_*2*4, 128, 0, stream>>>(qbh, kbh, vbh, adj, hs);
    out_kernel<<<B_*N_, 256, 0, stream>>>(hs, x, Wd, bd, gam, bet, out);
}

// Round 9
// 119.305 us; speedup vs baseline: 2.5377x; 1.1859x over previous
//
#include <hip/hip_runtime.h>
#include <cstdint>
#include <cstddef>

#define B_  8
#define T_  12
#define N_  250
#define D_  64
#define H_  8
#define HD_ 8

typedef short     bf16x8  __attribute__((ext_vector_type(8)));
typedef float     f32x16  __attribute__((ext_vector_type(16)));
typedef unsigned  u32x4   __attribute__((ext_vector_type(4)));
typedef float     f32x4u  __attribute__((ext_vector_type(4), aligned(4)));

#if __has_builtin(__builtin_amdgcn_exp2f)
#define EXP2(x) __builtin_amdgcn_exp2f(x)
#else
#define EXP2(x) exp2f(x)
#endif

__device__ __forceinline__ uint16_t f2bf(float f) {
    uint32_t u = __builtin_bit_cast(uint32_t, f);
    uint32_t r = (u + 0x7FFFu + ((u >> 16) & 1u)) >> 16;   // RNE
    return (uint16_t)r;
}

// ---------------- Kernel A: QKV projection -> bf16 operand buffers ----------
// qbh/kbh: [bt*8+h][256 rows (250 used)][8] bf16, row-major 16B rows.
// vbh:     [bt*8+h][8 d][256 m]            bf16 (V transposed per head).
__global__ __launch_bounds__(256) void qkv_kernel(
    const float* __restrict__ x,
    const float* __restrict__ Wq, const float* __restrict__ bq,
    const float* __restrict__ Wk, const float* __restrict__ bk,
    const float* __restrict__ Wv, const float* __restrict__ bv,
    uint16_t* __restrict__ qbh, uint16_t* __restrict__ kbh,
    uint16_t* __restrict__ vbh)
{
    __shared__ float WqT[64*64];
    __shared__ float WkT[64*64];
    __shared__ float WvT[64*64];
    __shared__ float xT[4][64][8];

    int tid = threadIdx.x;
    for (int i = tid; i < 4096; i += 256) {
        int d = i >> 6, j = i & 63;
        WqT[j*64 + d] = Wq[i];
        WkT[j*64 + d] = Wk[i];
        WvT[j*64 + d] = Wv[i];
    }
    __syncthreads();

    int wave = tid >> 6, lane = tid & 63;
    int row0 = blockIdx.x * 32 + wave * 8;   // 750*32 = 24000 rows

    #pragma unroll
    for (int rr = 0; rr < 8; ++rr)
        xT[wave][lane][rr] = x[(size_t)(row0 + rr)*64 + lane];

    float accq[8], acck[8], accv[8];
    float bqv = bq[lane], bkv = bk[lane], bvv = bv[lane];
    #pragma unroll
    for (int rr = 0; rr < 8; ++rr) { accq[rr]=bqv; acck[rr]=bkv; accv[rr]=bvv; }

    #pragma unroll 8
    for (int j = 0; j < 64; ++j) {
        float4 xa = *(const float4*)&xT[wave][j][0];
        float4 xb = *(const float4*)&xT[wave][j][4];
        float wq = WqT[j*64 + lane];
        float wk = WkT[j*64 + lane];
        float wv = WvT[j*64 + lane];
        float xr[8] = {xa.x, xa.y, xa.z, xa.w, xb.x, xb.y, xb.z, xb.w};
        #pragma unroll
        for (int rr = 0; rr < 8; ++rr) {
            accq[rr] = fmaf(xr[rr], wq, accq[rr]);
            acck[rr] = fmaf(xr[rr], wk, acck[rr]);
            accv[rr] = fmaf(xr[rr], wv, accv[rr]);
        }
    }

    int h = lane >> 3, dh = lane & 7;
    #pragma unroll
    for (int rr = 0; rr < 8; ++rr) {
        int row = row0 + rr;
        int bt = row / 250;
        int nn = row - bt*250;
        size_t hb = (size_t)(bt*8 + h);
        qbh[(hb*256 + nn)*8 + dh] = f2bf(accq[rr]);
        kbh[(hb*256 + nn)*8 + dh] = f2bf(acck[rr]);
        vbh[(hb*8 + dh)*256 + nn] = f2bf(accv[rr]);
    }
}

// ---------------- Kernel B: MFMA windowed attention (R5 structure + pipeline)
// grid = (b,t,h,ti,strip) = 9216 blocks x 128 thr (2 waves; wave = 32-n tile).
// Per wave: one ti chain. All per-mt operands (K frag, 2 V frags, 4 adj vec4)
// double-buffered one mt ahead; permlane asm non-volatile so the scheduler
// can pipeline across iterations.
__global__ __launch_bounds__(128, 2) void attn_kernel(
    const uint16_t* __restrict__ qbh, const uint16_t* __restrict__ kbh,
    const uint16_t* __restrict__ vbh, const float* __restrict__ adj,
    float* __restrict__ hs)
{
    const float S0e = 0.51006972338f;    // 8^-0.5 * log2(e)
    const float S1e = 0.18033688011f;    // 8^-1   * log2(e)
    const float S2e = 0.06375872168f;    // 8^-1.5 * log2(e)

    int tid  = threadIdx.x;
    int nt   = tid >> 6;
    int lane = tid & 63;
    int ln31 = lane & 31, hi = lane >> 5;

    int idx = blockIdx.x;
    int strip = idx & 3; idx >>= 2;
    int ti = idx % 3; idx /= 3;
    int h  = idx & 7; idx >>= 3;
    int t  = idx % 12;
    int b  = idx / 12;

    int t_k = (ti == 2) ? t : (t + 11) % 12;   // cumulative k/v shift
    int t_a = (t + ti + 11) % 12;              // fresh adj shift
    float scale = (ti == 0) ? S0e : (ti == 1) ? S1e : S2e;

    const uint16_t* qh = qbh + ((size_t)((b*12 + t  )*8 + h) * 256) * 8;
    const uint16_t* kh = kbh + ((size_t)((b*12 + t_k)*8 + h) * 256) * 8;
    const uint16_t* vh = vbh + ((size_t)((b*12 + t_k)*8 + h) * 8) * 256;

    int n0 = strip*64 + nt*32;
    int n  = n0 + ln31;
    int nc = n > 249 ? 249 : n;

    bf16x8 qf = *(const bf16x8*)(qh + (size_t)n * 8);
    bf16x8 z8 = {0,0,0,0,0,0,0,0};
    if (hi) qf = z8;

    const float* arow = adj + (size_t)(b*12 + t_a)*62500 + (size_t)nc*250;
    const uint16_t* vrp = vh + (size_t)(ln31 & 7) * 256;
    bool vzero = (ln31 >= 8);

    f32x16 zc;
    #pragma unroll
    for (int i = 0; i < 16; ++i) zc[i] = 0.f;
    f32x16 acc = zc;
    float zA = 0.f, zB = 0.f;         // split Z chain

    // prefetch mt=0 operands
    bf16x8 kf_c = *(const bf16x8*)(kh + (size_t)ln31 * 8);
    bf16x8 va_c = *(const bf16x8*)(vrp + hi*8);
    bf16x8 vb_c = *(const bf16x8*)(vrp + 16 + hi*8);
    f32x4u a0_c = *(const f32x4u*)(arow +      4*hi);
    f32x4u a1_c = *(const f32x4u*)(arow +  8 + 4*hi);
    f32x4u a2_c = *(const f32x4u*)(arow + 16 + 4*hi);
    f32x4u a3_c = *(const f32x4u*)(arow + 24 + 4*hi);

    #pragma unroll
    for (int mt = 0; mt < 8; ++mt) {
        // issue next-iteration loads first (static after unroll; no OOB)
        bf16x8 kf_n = kf_c, va_n = va_c, vb_n = vb_c;
        f32x4u a0_n = a0_c, a1_n = a1_c, a2_n = a2_c, a3_n = a3_c;
        if (mt < 7) {
            int m1 = mt*32 + 32;
            kf_n = *(const bf16x8*)(kh + (size_t)(m1 + ln31) * 8);
            va_n = *(const bf16x8*)(vrp + m1 + hi*8);
            vb_n = *(const bf16x8*)(vrp + m1 + 16 + hi*8);
            a0_n = *(const f32x4u*)(arow + m1 +      4*hi);
            a1_n = *(const f32x4u*)(arow + m1 +  8 + 4*hi);
            a2_n = *(const f32x4u*)(arow + m1 + 16 + 4*hi);
            a3_n = *(const f32x4u*)(arow + m1 + 24 + 4*hi);
        }

        bf16x8 kf = kf_c;
        if (hi) kf = z8;
        f32x16 s = __builtin_amdgcn_mfma_f32_32x32x16_bf16(kf, qf, zc, 0, 0, 0);

        bf16x8 vfa = va_c, vfb = vb_c;
        if (vzero) { vfa = z8; vfb = z8; }

        unsigned w[8];
        #pragma unroll
        for (int e = 0; e < 8; ++e) {
            int r0 = 2*e, r1 = 2*e + 1;
            float p0 = EXP2(s[r0] * scale);
            float p1 = EXP2(s[r1] * scale);
            float av0 = (r0 < 4) ? a0_c[r0 & 3] : (r0 < 8) ? a1_c[r0 & 3]
                      : (r0 < 12) ? a2_c[r0 & 3] : a3_c[r0 & 3];
            float av1 = (r1 < 4) ? a0_c[r1 & 3] : (r1 < 8) ? a1_c[r1 & 3]
                      : (r1 < 12) ? a2_c[r1 & 3] : a3_c[r1 & 3];
            if (mt == 7) {   // mask m-pad 250..255 (zero BOTH p and av)
                int c0 = (r0 & 3) + 8*(r0 >> 2) + 4*hi;
                int c1 = (r1 & 3) + 8*(r1 >> 2) + 4*hi;
                if (224 + c0 >= 250) { p0 = 0.f; av0 = 0.f; }
                if (224 + c1 >= 250) { p1 = 0.f; av1 = 0.f; }
            }
            zA += p0; zB += p1;
            float pa0 = p0 * av0, pa1 = p1 * av1;
            asm("v_cvt_pk_bf16_f32 %0, %1, %2"
                : "=v"(w[e]) : "v"(pa0), "v"(pa1));
        }
        // non-volatile: pure register ops, data deps preserve correctness,
        // scheduler free to pipeline loads around them
        asm("v_permlane32_swap_b32 %0, %1" : "+v"(w[2]), "+v"(w[0]));
        asm("v_permlane32_swap_b32 %0, %1" : "+v"(w[3]), "+v"(w[1]));
        asm("v_permlane32_swap_b32 %0, %1" : "+v"(w[6]), "+v"(w[4]));
        asm("v_permlane32_swap_b32 %0, %1" : "+v"(w[7]), "+v"(w[5]));

        u32x4 t1 = {w[0], w[1], w[2], w[3]};
        u32x4 t2 = {w[4], w[5], w[6], w[7]};
        bf16x8 pf1 = __builtin_bit_cast(bf16x8, t1);
        bf16x8 pf2 = __builtin_bit_cast(bf16x8, t2);

        acc = __builtin_amdgcn_mfma_f32_32x32x16_bf16(vfa, pf1, acc, 0, 0, 0);
        acc = __builtin_amdgcn_mfma_f32_32x32x16_bf16(vfb, pf2, acc, 0, 0, 0);

        kf_c = kf_n; va_c = va_n; vb_c = vb_n;
        a0_c = a0_n; a1_c = a1_n; a2_c = a2_n; a3_c = a3_n;
    }

    float z = zA + zB;
    float zf = z + __shfl_xor(z, 32);
    float inv = 1.0f / zf;

    if (n < 250) {
        float4 o;
        o.x = acc[0]*inv; o.y = acc[1]*inv; o.z = acc[2]*inv; o.w = acc[3]*inv;
        *(float4*)(hs + (((size_t)(b*36 + ti*12 + t)*250 + n)*64 + h*8 + hi*4)) = o;
    }
}

// ---------------- Kernel C: Wd head + residual + LayerNorm ----------------
__global__ __launch_bounds__(256) void out_kernel(
    const float* __restrict__ hsb, const float* __restrict__ x,
    const float* __restrict__ Wd, const float* __restrict__ bd,
    const float* __restrict__ gamma, const float* __restrict__ beta,
    float* __restrict__ out)
{
    __shared__ float hl[36*64];
    __shared__ float xl[12*64];

    int bn = blockIdx.x;
    int n = bn % 250, b = bn / 250;
    int tid = threadIdx.x;

    for (int i = tid; i < 36*64; i += 256) {
        int tw = i >> 6, d = i & 63;
        hl[i] = hsb[((size_t)(b*36 + tw)*250 + n)*64 + d];
    }
    for (int i = tid; i < 12*64; i += 256) {
        int t = i >> 6, d = i & 63;
        xl[i] = x[((size_t)(b*12 + t)*250 + n)*64 + d];
    }
    __syncthreads();

    int lane = tid & 63, wv = tid >> 6;
    float gg = gamma[lane], bb = beta[lane];

    for (int t = wv; t < 12; t += 4) {
        float acc = bd[t];
        const float* wd = Wd + t*36;
        #pragma unroll
        for (int tw = 0; tw < 36; ++tw)
            acc = fmaf(wd[tw], hl[tw*64 + lane], acc);
        float y = acc + xl[t*64 + lane];

        float s = y, s2 = y*y;
        #pragma unroll
        for (int o = 32; o >= 1; o >>= 1) {
            s  += __shfl_xor(s, o);
            s2 += __shfl_xor(s2, o);
        }
        float mu  = s * 0.015625f;
        float var = s2 * 0.015625f - mu*mu;
        out[((size_t)(b*12 + t)*250 + n)*64 + lane] =
            gg * (y - mu) * rsqrtf(var + 1e-5f) + bb;
    }
}

extern "C" void kernel_launch(void* const* d_in, const int* in_sizes, int n_in,
                              void* d_out, int out_size, void* d_ws, size_t ws_size,
                              hipStream_t stream)
{
    const float* x    = (const float*)d_in[0];
    // d_in[1] = ste : unused by the reference
    const float* adj  = (const float*)d_in[2];
    const float* Wq   = (const float*)d_in[3];
    const float* bq   = (const float*)d_in[4];
    const float* Wk   = (const float*)d_in[5];
    const float* bk   = (const float*)d_in[6];
    const float* Wv   = (const float*)d_in[7];
    const float* bv   = (const float*)d_in[8];
    const float* Wd   = (const float*)d_in[9];
    const float* bd   = (const float*)d_in[10];
    const float* gam  = (const float*)d_in[11];
    const float* bet  = (const float*)d_in[12];
    float* out = (float*)d_out;

    // ws layout (bytes): hs f32 [18,432,000] | qbh | kbh | vbh (bf16, each
    // 96*8 heads * 2048 elems = 3,145,728 B).
    float*    hs  = (float*)d_ws;
    uint16_t* qbh = (uint16_t*)((char*)d_ws + 18432000);
    uint16_t* kbh = qbh + 1572864;
    uint16_t* vbh = kbh + 1572864;

    qkv_kernel<<<750, 256, 0, stream>>>(x, Wq, bq, Wk, bk, Wv, bv, qbh, kbh, vbh);
    attn_kernel<<<B_*T_*H_*3*4, 128, 0, stream>>>(qbh, kbh, vbh, adj, hs);
    out_kernel<<<B_*N_, 256, 0, stream>>>(hs, x, Wd, bd, gam, bet, out);
}